// Round 9
// baseline (1215.387 us; speedup 1.0000x reference)
//
#include <hip/hip_runtime.h>
#include <math.h>

#define IN    64
#define UNITS 50
#define BBU   128
#define BATCH 256
#define TT    2048

typedef float f32x2 __attribute__((ext_vector_type(2)));

// ---------------------------------------------------------------------------
// DPP cross-lane add sources (VALU pipe):
//   0xB1 quad_perm xor1, 0x4E quad_perm xor2, 0x141 row_half_mirror (8-lane)
// ---------------------------------------------------------------------------
template <int CTRL>
__device__ __forceinline__ float dpp_mv(float v) {
    int r = __builtin_amdgcn_update_dpp(0, __builtin_bit_cast(int, v),
                                        CTRL, 0xF, 0xF, true);
    return __builtin_bit_cast(float, r);
}

// Opaque register pin: the asm result cannot be rematerialized.
__device__ __forceinline__ void pin2(f32x2 &v) {
    float a = v.x, b = v.y;
    asm volatile("" : "+v"(a), "+v"(b));
    v.x = a; v.y = b;
}

__device__ __forceinline__ f32x2 fma2(f32x2 a, f32x2 b, f32x2 c) {
    return __builtin_elementwise_fma(a, b, c);   // v_pk_fma_f32
}

// Barrier WITHOUT vmcnt drain: LDS ordering only. The in-flight xproj
// prefetch (vmcnt) keeps hiding across the step; compiler inserts its own
// vmcnt wait at the consuming use.
__device__ __forceinline__ void lds_barrier() {
    asm volatile("s_waitcnt lgkmcnt(0)\n\ts_barrier" ::: "memory");
}

// ---------------------------------------------------------------------------
// Kernel A (parallel): xproj[t][j] = b_bb[j] + sum_k x[255,t,k] * W_bb[k,j]
// ---------------------------------------------------------------------------
__global__ void xproj_kernel(const float* __restrict__ x,
                             const float* __restrict__ W_bb,
                             const float* __restrict__ b_bb,
                             float* __restrict__ xproj) {
    __shared__ float xr[IN];
    const int t = blockIdx.x;
    const int j = threadIdx.x;  // 0..127
    const float* xrow = x + ((size_t)(BATCH - 1) * TT + t) * IN;
    if (j < IN) xr[j] = xrow[j];
    __syncthreads();
    float acc = b_bb[j];
    #pragma unroll
    for (int k = 0; k < IN; ++k) acc = fmaf(xr[k], W_bb[k * BBU + j], acc);
    xproj[t * BBU + j] = acc;
}

// ---------------------------------------------------------------------------
// Kernel B (sequential): 1 block, 512 threads (8 waves, 2/SIMD), 2 barriers.
// amdgpu_waves_per_eu(2,2): closes the occupancy window so the allocator
// keeps the ~64 pinned weight floats in ARCH VGPRs (no AGPR shuffling).
//
// LDS (segment-staggered by 20 floats = conflict-free bank quads):
//   h_lds : 4 segs @20f, seg s holds units s*13..s*13+12 (+pads, zero)
//   bb_lds: 8 segs @20f, seg g holds bb[16g..16g+15]
//
// Phase 1: col j1=tid>>2 (0..127), quarter s1=tid&3 owns 13 h-values:
//   4x ds_read_b128 + 8 pk_fma, quad reduce (xor1,xor2), lecun_tanh,
//   s1==0 writes bb seg.
// Phase 2 (only octs with o2<50): lane g2=tid&7 owns bb seg of 16 for ALL
//   3 heads: 4x ds_read_b128 + 24 pk_fma, 8-lane reduce per head
//   (xor1,xor2,half_mirror), per-lane head select + ONE activation
//   (g0:tanh f1, g1:tanh f2, g2:sigmoid t), 2 DPP gathers -> g0 writes h.
// ---------------------------------------------------------------------------
__attribute__((amdgpu_flat_work_group_size(512, 512), amdgpu_waves_per_eu(2, 2)))
__global__ void cfc_seq_kernel(const float* __restrict__ W_bb,
                               const float* __restrict__ W_ff1, const float* __restrict__ b_ff1,
                               const float* __restrict__ W_ff2, const float* __restrict__ b_ff2,
                               const float* __restrict__ W_ta,  const float* __restrict__ b_ta,
                               const float* __restrict__ W_tb,  const float* __restrict__ b_tb,
                               const float* __restrict__ W_out, const float* __restrict__ b_out,
                               const float* __restrict__ xproj,
                               float* __restrict__ out) {
    __shared__ __align__(16) float h_lds[80];    // 4 segs at 20*s
    __shared__ __align__(16) float bb_lds[160];  // 8 segs at 20*g

    const int tid = threadIdx.x;

    // ---- phase-1 weights: 13 real (+3 zero) recurrent weights, as f32x2[8]
    const int j1 = tid >> 2;          // 0..127
    const int s1 = tid & 3;
    f32x2 wh2[8];
    #pragma unroll
    for (int q = 0; q < 16; ++q) {
        const int u = s1 * 13 + q;
        const float w = (q < 13 && u < UNITS) ? W_bb[(IN + u) * BBU + j1] : 0.f;
        if (q & 1) wh2[q >> 1].y = w; else wh2[q >> 1].x = w;
    }
    const int bbslot = 20 * (j1 >> 4) + (j1 & 15);

    // ---- phase-2 weights: seg g2 (16 floats) of all three heads, unit o2
    const int o2 = tid >> 3;          // 0..63 (unit, valid < 50)
    const int g2 = tid & 7;
    const int col = (o2 < UNITS) ? o2 : 0;
    f32x2 wf1[8], wf2[8], wtt[8];
    #pragma unroll
    for (int i = 0; i < 16; ++i) {
        const int row = g2 * 16 + i;
        const float a = W_ff1[row * UNITS + col];
        const float b = W_ff2[row * UNITS + col];
        const float c = W_ta[row * UNITS + col] + W_tb[row * UNITS + col];
        if (i & 1) { wf1[i >> 1].y = a; wf2[i >> 1].y = b; wtt[i >> 1].y = c; }
        else       { wf1[i >> 1].x = a; wf2[i >> 1].x = b; wtt[i >> 1].x = c; }
    }
    // per-lane bias + activation constants (g2==2 -> sigmoid, else tanh)
    float bias2;
    if (g2 == 0)      bias2 = b_ff1[col];
    else if (g2 == 1) bias2 = b_ff2[col];
    else              bias2 = b_ta[col] + b_tb[col];
    const float kact = (g2 == 2) ? 1.4426950409f : 2.8853900818f;
    const float cact = (g2 == 2) ? 1.f : 2.f;
    const int hslot = 20 * (col / 13) + (col % 13);

    // ---- pin every weight into a register (defeats remat/sinking)
    #pragma unroll
    for (int i = 0; i < 8; ++i) {
        pin2(wh2[i]); pin2(wf1[i]); pin2(wf2[i]); pin2(wtt[i]);
    }

    if (tid < 80) h_lds[tid] = 0.f;   // h + pads

    float xp_cur = xproj[j1];         // t = 0
    float xp_next;
    __syncthreads();

    for (int t = 0; t < TT; ++t) {
        // prefetch next step's xproj (consumed next iteration)
        {
            const int tn = (t + 1 < TT) ? (t + 1) : t;
            xp_next = xproj[tn * BBU + j1];
        }

        // ================= phase 1: backbone =================
        {
            const float4* h4 = (const float4*)(h_lds + s1 * 20);
            f32x2 acc = {(s1 == 0) ? xp_cur : 0.f, 0.f};
            #pragma unroll
            for (int k = 0; k < 4; ++k) {
                const float4 v = h4[k];
                const f32x2 lo = {v.x, v.y};
                const f32x2 hi = {v.z, v.w};
                acc = fma2(lo, wh2[2 * k + 0], acc);
                acc = fma2(hi, wh2[2 * k + 1], acc);
            }
            float a1 = acc.x + acc.y;
            a1 += dpp_mv<0xB1>(a1);
            a1 += dpp_mv<0x4E>(a1);
            // lecun_tanh: 1.7159*tanh(0.666x); 2*0.666*log2(e)=1.9216697945
            const float bbv = 1.7159f *
                (1.f - 2.f * __builtin_amdgcn_rcpf(
                     __builtin_amdgcn_exp2f(1.9216697945f * a1) + 1.f));
            if (s1 == 0) bb_lds[bbslot] = bbv;
        }
        lds_barrier();

        // ================= phase 2: heads + h update =================
        if (o2 < UNITS) {
            const float4* b4 = (const float4*)(bb_lds + g2 * 20);
            f32x2 af1 = {0.f, 0.f}, af2 = {0.f, 0.f}, att = {0.f, 0.f};
            #pragma unroll
            for (int k = 0; k < 4; ++k) {
                const float4 v = b4[k];
                const f32x2 lo = {v.x, v.y};
                const f32x2 hi = {v.z, v.w};
                af1 = fma2(lo, wf1[2 * k + 0], af1);
                af2 = fma2(lo, wf2[2 * k + 0], af2);
                att = fma2(lo, wtt[2 * k + 0], att);
                af1 = fma2(hi, wf1[2 * k + 1], af1);
                af2 = fma2(hi, wf2[2 * k + 1], af2);
                att = fma2(hi, wtt[2 * k + 1], att);
            }
            float sf1 = af1.x + af1.y;
            float sf2 = af2.x + af2.y;
            float stt = att.x + att.y;
            // 8-lane butterfly reduce per head
            sf1 += dpp_mv<0xB1>(sf1); sf1 += dpp_mv<0x4E>(sf1); sf1 += dpp_mv<0x141>(sf1);
            sf2 += dpp_mv<0xB1>(sf2); sf2 += dpp_mv<0x4E>(sf2); sf2 += dpp_mv<0x141>(sf2);
            stt += dpp_mv<0xB1>(stt); stt += dpp_mv<0x4E>(stt); stt += dpp_mv<0x141>(stt);
            // per-lane head select + ONE activation
            const float sel = (g2 == 0) ? sf1 : ((g2 == 1) ? sf2 : stt);
            const float a2 = sel + bias2;
            const float val = 1.f - cact * __builtin_amdgcn_rcpf(
                                  __builtin_amdgcn_exp2f(kact * a2) + 1.f);
            const float f2v = dpp_mv<0xB1>(val);   // g0 <- g1 (ff2)
            const float tiv = dpp_mv<0x4E>(val);   // g0 <- g2 (t_interp)
            if (g2 == 0) {
                // h = f1 + ti*(f2 - f1)
                h_lds[hslot] = fmaf(tiv, f2v - val, val);
            }
        }
        xp_cur = xp_next;
        lds_barrier();
    }

    // ---- readout: out = h @ W_out + b_out  (single wave)
    if (tid < 64) {
        float v = 0.f;
        if (tid < UNITS)
            v = h_lds[20 * (tid / 13) + (tid % 13)] * W_out[tid];
        #pragma unroll
        for (int off = 1; off < 64; off <<= 1)
            v += __shfl_xor(v, off);
        if (tid == 0) out[0] = v + b_out[0];
    }
}

// ---------------------------------------------------------------------------
extern "C" void kernel_launch(void* const* d_in, const int* in_sizes, int n_in,
                              void* d_out, int out_size, void* d_ws, size_t ws_size,
                              hipStream_t stream) {
    const float* x     = (const float*)d_in[0];
    const float* W_bb  = (const float*)d_in[1];
    const float* b_bb  = (const float*)d_in[2];
    const float* W_ff1 = (const float*)d_in[3];
    const float* b_ff1 = (const float*)d_in[4];
    const float* W_ff2 = (const float*)d_in[5];
    const float* b_ff2 = (const float*)d_in[6];
    const float* W_ta  = (const float*)d_in[7];
    const float* b_ta  = (const float*)d_in[8];
    const float* W_tb  = (const float*)d_in[9];
    const float* b_tb  = (const float*)d_in[10];
    const float* W_out = (const float*)d_in[11];
    const float* b_out = (const float*)d_in[12];
    float* out = (float*)d_out;

    float* xproj = (float*)d_ws;   // TT * BBU floats = 1 MiB

    xproj_kernel<<<TT, BBU, 0, stream>>>(x, W_bb, b_bb, xproj);
    cfc_seq_kernel<<<1, 512, 0, stream>>>(W_bb,
                                          W_ff1, b_ff1, W_ff2, b_ff2,
                                          W_ta, b_ta, W_tb, b_tb,
                                          W_out, b_out, xproj, out);
}